// Round 1
// baseline (423.791 us; speedup 1.0000x reference)
//
#include <hip/hip_runtime.h>

#define W 64
#define D 256
#define NH 8
#define HD 32

typedef unsigned short u16;
typedef __attribute__((ext_vector_type(8))) short bf16x8;
typedef __attribute__((ext_vector_type(4))) float f32x4;

__device__ __forceinline__ u16 f2bf(float f) {
    union { float f; unsigned u; } v; v.f = f;
    unsigned r = v.u + 0x7fffu + ((v.u >> 16) & 1u);
    return (u16)(r >> 16);
}

// ---------------- LDS layout (bytes) ----------------
// qk : [8 heads][64 tok][72] u16  (cols 0..31 = q, 32..63 = k, 8 pad)  73728
// vT : [8 heads][32 d ][72] u16  (row = d, cols = tok, 8 pad)          36864
// P  : [8 waves][16 q ][72] u16                                        18432
// xs : [64][264] u16  (x staging, later aliased by attn_out)           33792
// total 162816  (<= 160 KiB)
#define OFF_QK 0
#define QK_ROW 72
#define OFF_VT 73728
#define VT_ROW 72
#define OFF_P  110592
#define P_ROW  72
#define OFF_XS 129024
#define XS_ROW 264

__global__ __launch_bounds__(512, 2) void win_attn(
    const float* __restrict__ x, const float* __restrict__ bqkv,
    const float* __restrict__ bproj, const float* __restrict__ relb,
    const u16* __restrict__ wqkvT, const u16* __restrict__ wprojT,
    float* __restrict__ out)
{
    __shared__ __align__(16) char smem[162816];

    const int tid  = threadIdx.x;
    const int lane = tid & 63;
    const int wv   = tid >> 6;      // wave index == head index
    const int l15  = lane & 15;
    const int g    = lane >> 4;
    const int w    = blockIdx.x;

    u16* qk = (u16*)(smem + OFF_QK);
    u16* vT = (u16*)(smem + OFF_VT);
    u16* Pb = (u16*)(smem + OFF_P) + wv * 16 * P_ROW;
    u16* xs = (u16*)(smem + OFF_XS);

    const f32x4 z4 = {0.f, 0.f, 0.f, 0.f};

    // ---------- Phase 0: stage x window -> LDS (bf16, padded rows) ----------
    const float* xw = x + (size_t)w * (W * D);
    #pragma unroll
    for (int i = 0; i < 8; ++i) {
        int e   = i * 2048 + tid * 4;
        int row = e >> 8, col = e & 255;
        float4 v = *(const float4*)(xw + e);
        ushort4 b;
        b.x = f2bf(v.x); b.y = f2bf(v.y); b.z = f2bf(v.z); b.w = f2bf(v.w);
        *(ushort4*)(xs + row * XS_ROW + col) = b;
    }
    __syncthreads();

    // ---------- Phase 1: x A-fragments -> registers (all of the 64x256 tile) ----------
    bf16x8 afr[4][8];
    #pragma unroll
    for (int rt = 0; rt < 4; ++rt)
        #pragma unroll
        for (int ks = 0; ks < 8; ++ks)
            afr[rt][ks] = *(const bf16x8*)((const char*)smem + OFF_XS +
                           (16 * rt + l15) * (XS_ROW * 2) + ks * 64 + g * 16);
    __syncthreads();   // xs region is reused as attn_out later

    // ---------- Phase 2: QKV GEMM (wave h owns head h's q,k,v columns) ----------
    #pragma unroll
    for (int mc = 0; mc < 6; ++mc) {
        const int mat = mc >> 1, ct = mc & 1;         // mat: 0=q 1=k 2=v
        const int n0  = mat * 256 + wv * 32 + ct * 16;
        const u16* brow = wqkvT + (size_t)(n0 + l15) * 256;
        f32x4 acc[4] = {z4, z4, z4, z4};
        #pragma unroll
        for (int ks = 0; ks < 8; ++ks) {
            bf16x8 bf = *(const bf16x8*)(brow + ks * 32 + g * 8);
            #pragma unroll
            for (int rt = 0; rt < 4; ++rt)
                acc[rt] = __builtin_amdgcn_mfma_f32_16x16x32_bf16(afr[rt][ks], bf, acc[rt], 0, 0, 0);
        }
        const float bias = bqkv[n0 + l15];
        if (mat < 2) {   // q or k: [tok][d] row-major per head
            u16* dst = qk + wv * 64 * QK_ROW + mat * 32 + ct * 16 + l15;
            #pragma unroll
            for (int rt = 0; rt < 4; ++rt)
                #pragma unroll
                for (int r = 0; r < 4; ++r)
                    dst[(16 * rt + 4 * g + r) * QK_ROW] = f2bf(acc[rt][r] + bias);
        } else {         // v transposed: [d][tok]
            u16* dst = vT + wv * 32 * VT_ROW + (ct * 16 + l15) * VT_ROW;
            #pragma unroll
            for (int rt = 0; rt < 4; ++rt)
                #pragma unroll
                for (int r = 0; r < 4; ++r)
                    dst[16 * rt + 4 * g + r] = f2bf(acc[rt][r] + bias);
        }
    }
    // q,k,v are wave-private: no barrier needed.

    // ---------- Phase 3: attention for head wv ----------
    const u16* qbase = qk + wv * 64 * QK_ROW;
    bf16x8 qf[4], kf[4];
    #pragma unroll
    for (int t = 0; t < 4; ++t) {
        qf[t] = *(const bf16x8*)(qbase + (16 * t + l15) * QK_ROW + g * 8);
        kf[t] = *(const bf16x8*)(qbase + (16 * t + l15) * QK_ROW + 32 + g * 8);
    }
    bf16x8 vf[2][2];
    #pragma unroll
    for (int ks = 0; ks < 2; ++ks)
        #pragma unroll
        for (int cd = 0; cd < 2; ++cd)
            vf[ks][cd] = *(const bf16x8*)(vT + wv * 32 * VT_ROW +
                          (16 * cd + l15) * VT_ROW + ks * 32 + g * 8);

    const float* biasrow = relb + wv * 127;
    const float scale = 0.17677669529663687f;   // 1/sqrt(32)
    u16* ao = xs;   // attn_out aliases the dead x staging region

    #pragma unroll
    for (int rt = 0; rt < 4; ++rt) {
        // scores for this 16-row tile: S[16rt..][0..64)
        f32x4 s[4];
        #pragma unroll
        for (int ct = 0; ct < 4; ++ct)
            s[ct] = __builtin_amdgcn_mfma_f32_16x16x32_bf16(qf[rt], kf[ct], z4, 0, 0, 0);

        float sv[4][4];   // [ct][r]
        #pragma unroll
        for (int ct = 0; ct < 4; ++ct) {
            const int k_tok = 16 * ct + l15;
            #pragma unroll
            for (int r = 0; r < 4; ++r) {
                const int q_tok = 16 * rt + 4 * g + r;
                sv[ct][r] = s[ct][r] * scale + biasrow[k_tok - q_tok + 63];
            }
        }
        #pragma unroll
        for (int r = 0; r < 4; ++r) {
            float m = fmaxf(fmaxf(sv[0][r], sv[1][r]), fmaxf(sv[2][r], sv[3][r]));
            #pragma unroll
            for (int mask = 1; mask <= 8; mask <<= 1)
                m = fmaxf(m, __shfl_xor(m, mask, 64));
            float e0 = __expf(sv[0][r] - m), e1 = __expf(sv[1][r] - m);
            float e2 = __expf(sv[2][r] - m), e3 = __expf(sv[3][r] - m);
            float sum = (e0 + e1) + (e2 + e3);
            #pragma unroll
            for (int mask = 1; mask <= 8; mask <<= 1)
                sum += __shfl_xor(sum, mask, 64);
            const float inv = 1.0f / sum;
            const int prow = 4 * g + r;
            Pb[prow * P_ROW +      l15] = f2bf(e0 * inv);
            Pb[prow * P_ROW + 16 + l15] = f2bf(e1 * inv);
            Pb[prow * P_ROW + 32 + l15] = f2bf(e2 * inv);
            Pb[prow * P_ROW + 48 + l15] = f2bf(e3 * inv);
        }
        // PV for this row tile
        bf16x8 pf0 = *(const bf16x8*)(Pb + l15 * P_ROW + g * 8);
        bf16x8 pf1 = *(const bf16x8*)(Pb + l15 * P_ROW + 32 + g * 8);
        #pragma unroll
        for (int cd = 0; cd < 2; ++cd) {
            f32x4 o = __builtin_amdgcn_mfma_f32_16x16x32_bf16(pf0, vf[0][cd], z4, 0, 0, 0);
            o = __builtin_amdgcn_mfma_f32_16x16x32_bf16(pf1, vf[1][cd], o, 0, 0, 0);
            #pragma unroll
            for (int r = 0; r < 4; ++r)
                ao[(16 * rt + 4 * g + r) * XS_ROW + wv * 32 + 16 * cd + l15] = f2bf(o[r]);
        }
    }
    __syncthreads();   // attn_out complete (cross-wave consumed by proj)

    // ---------- Phase 4: output projection ----------
    bf16x8 pfr[4][8];
    #pragma unroll
    for (int rt = 0; rt < 4; ++rt)
        #pragma unroll
        for (int ks = 0; ks < 8; ++ks)
            pfr[rt][ks] = *(const bf16x8*)((const char*)smem + OFF_XS +
                           (16 * rt + l15) * (XS_ROW * 2) + ks * 64 + g * 16);

    f32x4 pacc[2][4] = {{z4, z4, z4, z4}, {z4, z4, z4, z4}};
    #pragma unroll
    for (int ct = 0; ct < 2; ++ct) {
        const u16* brow = wprojT + (size_t)(wv * 32 + ct * 16 + l15) * 256;
        #pragma unroll
        for (int ks = 0; ks < 8; ++ks) {
            bf16x8 bf = *(const bf16x8*)(brow + ks * 32 + g * 8);
            #pragma unroll
            for (int rt = 0; rt < 4; ++rt)
                pacc[ct][rt] = __builtin_amdgcn_mfma_f32_16x16x32_bf16(pfr[rt][ks], bf, pacc[ct][rt], 0, 0, 0);
        }
    }
    float* outw = out + (size_t)w * (W * D);
    #pragma unroll
    for (int ct = 0; ct < 2; ++ct) {
        const int n = wv * 32 + ct * 16 + l15;
        const float bp = bproj[n];
        #pragma unroll
        for (int rt = 0; rt < 4; ++rt)
            #pragma unroll
            for (int r = 0; r < 4; ++r)
                outw[(16 * rt + 4 * g + r) * D + n] = pacc[ct][rt][r] + bp;
    }
}

// Transpose + bf16-convert the weight matrices into workspace (L2-resident).
__global__ void prep_weights(const float* __restrict__ wqkv, const float* __restrict__ wproj,
                             u16* __restrict__ wqkvT, u16* __restrict__ wprojT)
{
    int i = blockIdx.x * 256 + threadIdx.x;
    if (i < 768 * 256) {
        int n = i >> 8, k = i & 255;
        wqkvT[i] = f2bf(wqkv[k * 768 + n]);
    } else {
        int j = i - 768 * 256;
        int n = j >> 8, k = j & 255;
        wprojT[j] = f2bf(wproj[k * 256 + n]);
    }
}

extern "C" void kernel_launch(void* const* d_in, const int* in_sizes, int n_in,
                              void* d_out, int out_size, void* d_ws, size_t ws_size,
                              hipStream_t stream)
{
    const float* x     = (const float*)d_in[0];
    const float* wqkv  = (const float*)d_in[1];
    const float* bqkv  = (const float*)d_in[2];
    const float* wproj = (const float*)d_in[3];
    const float* bproj = (const float*)d_in[4];
    const float* relb  = (const float*)d_in[5];

    u16* wqkvT = (u16*)d_ws;                  // 768*256 bf16
    u16* wprojT = wqkvT + 768 * 256;          // 256*256 bf16

    prep_weights<<<1024, 256, 0, stream>>>(wqkv, wproj, wqkvT, wprojT);

    const int nwin = in_sizes[0] / (W * D);   // 4096
    win_attn<<<nwin, 512, 0, stream>>>(x, bqkv, bproj, relb, wqkvT, wprojT, (float*)d_out);
}